// Round 5
// baseline (145.860 us; speedup 1.0000x reference)
//
#include <hip/hip_runtime.h>

#define L_SEQ   2048
#define NBATCH  4
#define DM      512
#define DS      16
#define DR      32
#define NROWS   8192
#define NBDN    32768         // NBATCH*DM*DS chains
#define NCH     128           // chunks
#define CL      16            // chunk length
#define LOG2E   1.4426950408889634f

// ws layout (float offsets)
#define WS_XC    0            // 4194304  xc row-major [b,l][d]
#define WS_XDBL  4194304      // 524288   x_dbl [row][64] (dt-raw | B | C)
#define WS_WXT   4718592      // 32768    WxT[d][j]
#define WS_WDTT  4751360      // 16384    WdtT[r][d]
#define WS_A2    4767744      // 8192     A2[d][n] = -exp(A_log)*log2e
#define WS_DTSUM 4775936      // 262144   dtsum[c][b*DM+d]
#define WS_S     5038080      // 4194304  S[c][chain]; scan2 rewrites in-place to Hin
#define WS_PART  WS_S         // 2097152  proj1 partials alias S (dead until scan1)
// total 9232384 floats = 36.9 MB

// ---------------- weight transposes + A2 precompute ----------------
__global__ void k_prep(const float* __restrict__ Wx, const float* __restrict__ Wdt,
                       const float* __restrict__ A_log,
                       float* __restrict__ WxT, float* __restrict__ WdtT,
                       float* __restrict__ A2) {
    int idx = blockIdx.x * 256 + threadIdx.x;
    if (idx < DM * 64) {                 // WxT[d][j] = Wx[j][d]
        int d = idx >> 6, j = idx & 63;
        WxT[idx] = Wx[j * DM + d];
    }
    if (idx < DR * DM) {                 // WdtT[r][d] = Wdt[d][r]
        int r = idx >> 9, d = idx & 511;
        WdtT[idx] = Wdt[d * DR + r];
    }
    if (idx < DM * DS)                   // A2[d][n]
        A2[idx] = -__expf(A_log[idx]) * LOG2E;
}

// ---------------- depthwise causal conv1d (K=4), float4 over d ----------------
__global__ void k_conv(const float* __restrict__ x, const float* __restrict__ convw,
                       const float* __restrict__ convb, float* __restrict__ xc) {
    int idx = blockIdx.x * 256 + threadIdx.x;      // 0..1048575
    int dq  = idx & 127;
    int row = idx >> 7;
    int l   = row & (L_SEQ - 1);
    const float4* wp = (const float4*)convw;       // [d] -> (k0,k1,k2,k3)
    float4 w0 = wp[dq * 4 + 0], w1 = wp[dq * 4 + 1];
    float4 w2 = wp[dq * 4 + 2], w3 = wp[dq * 4 + 3];
    float4 acc = ((const float4*)convb)[dq];
    const float* xr = x + (size_t)row * DM + dq * 4;
    float4 xv = *(const float4*)xr;
    acc.x = fmaf(xv.x, w0.w, acc.x); acc.y = fmaf(xv.y, w1.w, acc.y);
    acc.z = fmaf(xv.z, w2.w, acc.z); acc.w = fmaf(xv.w, w3.w, acc.w);
    if (l >= 1) {
        xv = *(const float4*)(xr - DM);
        acc.x = fmaf(xv.x, w0.z, acc.x); acc.y = fmaf(xv.y, w1.z, acc.y);
        acc.z = fmaf(xv.z, w2.z, acc.z); acc.w = fmaf(xv.w, w3.z, acc.w);
    }
    if (l >= 2) {
        xv = *(const float4*)(xr - 2 * DM);
        acc.x = fmaf(xv.x, w0.y, acc.x); acc.y = fmaf(xv.y, w1.y, acc.y);
        acc.z = fmaf(xv.z, w2.y, acc.z); acc.w = fmaf(xv.w, w3.y, acc.w);
    }
    if (l >= 3) {
        xv = *(const float4*)(xr - 3 * DM);
        acc.x = fmaf(xv.x, w0.x, acc.x); acc.y = fmaf(xv.y, w1.x, acc.y);
        acc.z = fmaf(xv.z, w2.x, acc.z); acc.w = fmaf(xv.w, w3.x, acc.w);
    }
    *(float4*)(xc + (size_t)row * DM + dq * 4) = acc;
}

// ---------------- proj1a: K-split x4 partial GEMM ----------------
__global__ void k_proj1a(const float* __restrict__ xc, const float* __restrict__ WxT,
                         float* __restrict__ part) {
    int wv = __builtin_amdgcn_readfirstlane((int)(threadIdx.x >> 6));
    int j  = threadIdx.x & 63;
    int ks = blockIdx.x & 3;
    int rows_base = (blockIdx.x >> 2) * 32 + wv * 8;
    int k0 = ks * 128;
    const float* xcrow = xc + (size_t)rows_base * DM + k0;
    const float* wp    = WxT + (size_t)k0 * 64 + j;
    float acc[8] = {0.f, 0.f, 0.f, 0.f, 0.f, 0.f, 0.f, 0.f};
    #pragma unroll 8
    for (int d = 0; d < 128; ++d) {
        float w = wp[d * 64];
        #pragma unroll
        for (int ri = 0; ri < 8; ++ri)
            acc[ri] = fmaf(xcrow[ri * DM + d], w, acc[ri]);
    }
    float* pp = part + (size_t)ks * (NROWS * 64) + (size_t)rows_base * 64 + j;
    #pragma unroll
    for (int ri = 0; ri < 8; ++ri)
        pp[ri * 64] = acc[ri];
}

// ---------------- proj1b: reduce 4 partials -> xdbl ----------------
__global__ void k_proj1b(const float* __restrict__ part, float* __restrict__ xdbl) {
    int idx = blockIdx.x * 256 + threadIdx.x;      // 0..524287
    xdbl[idx] = (part[idx] + part[idx + 524288])
              + (part[idx + 2 * 524288] + part[idx + 3 * 524288]);
}

// ---------------- scan1: fused dt-compute + per-chunk local scan ----------------
// lane = d (64/wave), 16 states in regs. Writes S[c][chain] and dtsum[c][bd].
__global__ void __launch_bounds__(256) k_scan1(
        const float* __restrict__ xc, const float* __restrict__ xdbl,
        const float* __restrict__ WdtT, const float* __restrict__ dtb,
        const float* __restrict__ A2, float* __restrict__ S,
        float* __restrict__ dtsum) {
    int lane = threadIdx.x & 63;
    int w    = threadIdx.x >> 6;
    int half = blockIdx.x & 1;
    int c    = blockIdx.x >> 1;
    int b    = blockIdx.y;
    int d    = (half * 4 + w) * 64 + lane;

    float W[DR];
    #pragma unroll
    for (int r = 0; r < DR; ++r) W[r] = WdtT[r * DM + d];
    float bias = dtb[d];
    float a2[16];
    {
        const float4* ap = (const float4*)(A2 + (size_t)d * DS);
        #pragma unroll
        for (int q = 0; q < 4; ++q) {
            float4 v = ap[q];
            a2[q*4+0] = v.x; a2[q*4+1] = v.y; a2[q*4+2] = v.z; a2[q*4+3] = v.w;
        }
    }
    float h[16];
    #pragma unroll
    for (int n = 0; n < 16; ++n) h[n] = 0.f;
    float dsum = 0.f;

    int l0 = c * CL;
    const float* xcp = xc   + ((size_t)(b * L_SEQ + l0)) * DM + d;
    const float* xdp = xdbl + ((size_t)(b * L_SEQ + l0)) * 64;

    #pragma unroll 4
    for (int i = 0; i < CL; ++i) {
        const float* xr = xdp + i * 64;
        float z = bias;
        #pragma unroll
        for (int r = 0; r < DR; ++r) z = fmaf(xr[r], W[r], z);
        float dt = fmaxf(z, 0.f) + log1pf(__expf(-fabsf(z)));   // softplus
        float xv = xcp[(size_t)i * DM];
        float u  = dt * xv;
        dsum += dt;
        const float4* Bq = (const float4*)(xr + DR);
        #pragma unroll
        for (int q = 0; q < 4; ++q) {
            float4 B4 = Bq[q];
            float dA;
            dA = exp2f(dt * a2[q*4+0]); h[q*4+0] = fmaf(dA, h[q*4+0], u * B4.x);
            dA = exp2f(dt * a2[q*4+1]); h[q*4+1] = fmaf(dA, h[q*4+1], u * B4.y);
            dA = exp2f(dt * a2[q*4+2]); h[q*4+2] = fmaf(dA, h[q*4+2], u * B4.z);
            dA = exp2f(dt * a2[q*4+3]); h[q*4+3] = fmaf(dA, h[q*4+3], u * B4.w);
        }
    }

    size_t tb = (size_t)c * NBDN + ((size_t)(b * DM + d)) * DS;
    float4* Sp = (float4*)(S + tb);
    #pragma unroll
    for (int q = 0; q < 4; ++q) {
        float4 sv; sv.x = h[q*4+0]; sv.y = h[q*4+1]; sv.z = h[q*4+2]; sv.w = h[q*4+3];
        Sp[q] = sv;
    }
    dtsum[c * (NBATCH * DM) + b * DM + d] = dsum;
}

// ---------------- scan2: cross-chunk prefix; P from dtsum; in-place Hin ----------------
__global__ void k_scan2(const float* __restrict__ dtsum, const float* __restrict__ A2,
                        float* __restrict__ S) {
    int t  = blockIdx.x * 256 + threadIdx.x;       // 0..32767
    float a2 = A2[t & (DM * DS - 1)];
    int bd = t >> 4;                               // b*DM+d in [0,2048)
    float H = 0.f;
    #pragma unroll 8
    for (int c = 0; c < NCH; ++c) {
        float p = exp2f(a2 * dtsum[c * (NBATCH * DM) + bd]);
        float s = S[(size_t)c * NBDN + t];
        S[(size_t)c * NBDN + t] = H;               // Hin for chunk c
        H = fmaf(p, H, s);
    }
}

// ---------------- scan3: fused dt-recompute + scan from Hin + y emit ----------------
__global__ void __launch_bounds__(256) k_scan3(
        const float* __restrict__ xc, const float* __restrict__ xdbl,
        const float* __restrict__ WdtT, const float* __restrict__ dtb,
        const float* __restrict__ A2, const float* __restrict__ Dvec,
        const float* __restrict__ Hin, float* __restrict__ out) {
    int lane = threadIdx.x & 63;
    int w    = threadIdx.x >> 6;
    int half = blockIdx.x & 1;
    int c    = blockIdx.x >> 1;
    int b    = blockIdx.y;
    int d    = (half * 4 + w) * 64 + lane;

    float W[DR];
    #pragma unroll
    for (int r = 0; r < DR; ++r) W[r] = WdtT[r * DM + d];
    float bias = dtb[d];
    float a2[16];
    {
        const float4* ap = (const float4*)(A2 + (size_t)d * DS);
        #pragma unroll
        for (int q = 0; q < 4; ++q) {
            float4 v = ap[q];
            a2[q*4+0] = v.x; a2[q*4+1] = v.y; a2[q*4+2] = v.z; a2[q*4+3] = v.w;
        }
    }
    float Dv = Dvec[d];
    float h[16];
    {
        const float4* hp = (const float4*)(Hin + (size_t)c * NBDN + ((size_t)(b * DM + d)) * DS);
        #pragma unroll
        for (int q = 0; q < 4; ++q) {
            float4 v = hp[q];
            h[q*4+0] = v.x; h[q*4+1] = v.y; h[q*4+2] = v.z; h[q*4+3] = v.w;
        }
    }

    int l0 = c * CL;
    const float* xcp = xc   + ((size_t)(b * L_SEQ + l0)) * DM + d;
    const float* xdp = xdbl + ((size_t)(b * L_SEQ + l0)) * 64;
    float* op = out + ((size_t)(b * L_SEQ + l0)) * DM + d;

    #pragma unroll 4
    for (int i = 0; i < CL; ++i) {
        const float* xr = xdp + i * 64;
        float z = bias;
        #pragma unroll
        for (int r = 0; r < DR; ++r) z = fmaf(xr[r], W[r], z);
        float dt = fmaxf(z, 0.f) + log1pf(__expf(-fabsf(z)));
        float xv = xcp[(size_t)i * DM];
        float u  = dt * xv;
        float y  = xv * Dv;
        const float4* Bq = (const float4*)(xr + DR);
        #pragma unroll
        for (int q = 0; q < 4; ++q) {
            float4 B4 = Bq[q];
            float4 C4 = Bq[q + 4];
            float dA;
            dA = exp2f(dt * a2[q*4+0]); h[q*4+0] = fmaf(dA, h[q*4+0], u * B4.x);
            y = fmaf(h[q*4+0], C4.x, y);
            dA = exp2f(dt * a2[q*4+1]); h[q*4+1] = fmaf(dA, h[q*4+1], u * B4.y);
            y = fmaf(h[q*4+1], C4.y, y);
            dA = exp2f(dt * a2[q*4+2]); h[q*4+2] = fmaf(dA, h[q*4+2], u * B4.z);
            y = fmaf(h[q*4+2], C4.z, y);
            dA = exp2f(dt * a2[q*4+3]); h[q*4+3] = fmaf(dA, h[q*4+3], u * B4.w);
            y = fmaf(h[q*4+3], C4.w, y);
        }
        op[(size_t)i * DM] = y;
    }
}

extern "C" void kernel_launch(void* const* d_in, const int* in_sizes, int n_in,
                              void* d_out, int out_size, void* d_ws, size_t ws_size,
                              hipStream_t stream) {
    const float* x      = (const float*)d_in[0];
    const float* A_log  = (const float*)d_in[1];
    const float* Dvec   = (const float*)d_in[2];
    const float* Wx     = (const float*)d_in[3];
    const float* Wdt    = (const float*)d_in[4];
    const float* dtb    = (const float*)d_in[5];
    const float* convw  = (const float*)d_in[6];
    const float* convb  = (const float*)d_in[7];
    float* out = (float*)d_out;
    float* ws  = (float*)d_ws;

    float* xc    = ws + WS_XC;
    float* xdbl  = ws + WS_XDBL;
    float* WxT   = ws + WS_WXT;
    float* WdtT  = ws + WS_WDTT;
    float* A2    = ws + WS_A2;
    float* dtsum = ws + WS_DTSUM;
    float* S     = ws + WS_S;
    float* part  = ws + WS_PART;   // aliases S; dead before k_scan1 writes S

    k_prep<<<128, 256, 0, stream>>>(Wx, Wdt, A_log, WxT, WdtT, A2);
    k_conv<<<4096, 256, 0, stream>>>(x, convw, convb, xc);
    k_proj1a<<<1024, 256, 0, stream>>>(xc, WxT, part);
    k_proj1b<<<2048, 256, 0, stream>>>(part, xdbl);
    k_scan1<<<dim3(2 * NCH, NBATCH), 256, 0, stream>>>(xc, xdbl, WdtT, dtb, A2, S, dtsum);
    k_scan2<<<128, 256, 0, stream>>>(dtsum, A2, S);
    k_scan3<<<dim3(2 * NCH, NBATCH), 256, 0, stream>>>(xc, xdbl, WdtT, dtb, A2, Dvec, S, out);
}

// Round 6
// 123.683 us; speedup vs baseline: 1.1793x; 1.1793x over previous
//
#include <hip/hip_runtime.h>

#define L_SEQ   2048
#define NBATCH  4
#define DM      512
#define DS      16
#define DR      32
#define NROWS   8192
#define NBDN    32768         // NBATCH*DM*DS chains
#define NCH     64            // chunks
#define CL      32            // chunk length
#define LOG2E   1.4426950408889634f

// ws layout (float offsets)
#define WS_XC    0            // 4194304  xc row-major [b,l][d]
#define WS_DT    4194304      // 4194304  dt row-major [b,l][d]
#define WS_XDBL  8388608      // 524288   x_dbl [row][64] (dt-raw | B | C)
#define WS_WXT   8912896      // 32768    WxT[d][j]
#define WS_WDTT  8945664      // 16384    WdtT[r][d]
#define WS_A2    8962048      // 8192     A2[d][n] = -exp(A_log)*log2e
#define WS_DTSUM 8970240      // 131072   dtsum[c][b*DM+d]
#define WS_S     9101312      // 2097152  S[c][chain]; scan2 rewrites in-place to Hin
#define WS_PART  WS_S         // 2097152  proj1 partials alias S (dead before scan1)
// total 11198464 floats = 44.8 MB

// ---------------- weight transposes + A2 precompute ----------------
__global__ void k_prep(const float* __restrict__ Wx, const float* __restrict__ Wdt,
                       const float* __restrict__ A_log,
                       float* __restrict__ WxT, float* __restrict__ WdtT,
                       float* __restrict__ A2) {
    int idx = blockIdx.x * 256 + threadIdx.x;
    if (idx < DM * 64) {                 // WxT[d][j] = Wx[j][d]
        int d = idx >> 6, j = idx & 63;
        WxT[idx] = Wx[j * DM + d];
    }
    if (idx < DR * DM) {                 // WdtT[r][d] = Wdt[d][r]
        int r = idx >> 9, d = idx & 511;
        WdtT[idx] = Wdt[d * DR + r];
    }
    if (idx < DM * DS)                   // A2[d][n]
        A2[idx] = -__expf(A_log[idx]) * LOG2E;
}

// ---------------- depthwise causal conv1d (K=4), float4 over d ----------------
__global__ void k_conv(const float* __restrict__ x, const float* __restrict__ convw,
                       const float* __restrict__ convb, float* __restrict__ xc) {
    int idx = blockIdx.x * 256 + threadIdx.x;      // 0..1048575
    int dq  = idx & 127;
    int row = idx >> 7;
    int l   = row & (L_SEQ - 1);
    const float4* wp = (const float4*)convw;       // [d] -> (k0,k1,k2,k3)
    float4 w0 = wp[dq * 4 + 0], w1 = wp[dq * 4 + 1];
    float4 w2 = wp[dq * 4 + 2], w3 = wp[dq * 4 + 3];
    float4 acc = ((const float4*)convb)[dq];
    const float* xr = x + (size_t)row * DM + dq * 4;
    float4 xv = *(const float4*)xr;
    acc.x = fmaf(xv.x, w0.w, acc.x); acc.y = fmaf(xv.y, w1.w, acc.y);
    acc.z = fmaf(xv.z, w2.w, acc.z); acc.w = fmaf(xv.w, w3.w, acc.w);
    if (l >= 1) {
        xv = *(const float4*)(xr - DM);
        acc.x = fmaf(xv.x, w0.z, acc.x); acc.y = fmaf(xv.y, w1.z, acc.y);
        acc.z = fmaf(xv.z, w2.z, acc.z); acc.w = fmaf(xv.w, w3.z, acc.w);
    }
    if (l >= 2) {
        xv = *(const float4*)(xr - 2 * DM);
        acc.x = fmaf(xv.x, w0.y, acc.x); acc.y = fmaf(xv.y, w1.y, acc.y);
        acc.z = fmaf(xv.z, w2.y, acc.z); acc.w = fmaf(xv.w, w3.y, acc.w);
    }
    if (l >= 3) {
        xv = *(const float4*)(xr - 3 * DM);
        acc.x = fmaf(xv.x, w0.x, acc.x); acc.y = fmaf(xv.y, w1.x, acc.y);
        acc.z = fmaf(xv.z, w2.x, acc.z); acc.w = fmaf(xv.w, w3.x, acc.w);
    }
    *(float4*)(xc + (size_t)row * DM + dq * 4) = acc;
}

// ---------------- proj1a: K-split x4 partial GEMM ----------------
__global__ void k_proj1a(const float* __restrict__ xc, const float* __restrict__ WxT,
                         float* __restrict__ part) {
    int wv = __builtin_amdgcn_readfirstlane((int)(threadIdx.x >> 6));
    int j  = threadIdx.x & 63;
    int ks = blockIdx.x & 3;
    int rows_base = (blockIdx.x >> 2) * 32 + wv * 8;
    int k0 = ks * 128;
    const float* xcrow = xc + (size_t)rows_base * DM + k0;
    const float* wp    = WxT + (size_t)k0 * 64 + j;
    float acc[8] = {0.f, 0.f, 0.f, 0.f, 0.f, 0.f, 0.f, 0.f};
    #pragma unroll 8
    for (int d = 0; d < 128; ++d) {
        float w = wp[d * 64];
        #pragma unroll
        for (int ri = 0; ri < 8; ++ri)
            acc[ri] = fmaf(xcrow[ri * DM + d], w, acc[ri]);
    }
    float* pp = part + (size_t)ks * (NROWS * 64) + (size_t)rows_base * 64 + j;
    #pragma unroll
    for (int ri = 0; ri < 8; ++ri)
        pp[ri * 64] = acc[ri];
}

// ---------------- proj1b: reduce 4 partials -> xdbl ----------------
__global__ void k_proj1b(const float* __restrict__ part, float* __restrict__ xdbl) {
    int idx = blockIdx.x * 256 + threadIdx.x;      // 0..524287
    xdbl[idx] = (part[idx] + part[idx + 524288])
              + (part[idx + 2 * 524288] + part[idx + 3 * 524288]);
}

// ---------------- proj2 + softplus: 4 outputs/thread, float4 weights ----------------
__global__ void k_proj2(const float* __restrict__ xdbl, const float* __restrict__ WdtT,
                        const float* __restrict__ dtb, float* __restrict__ dtw) {
    int idx = blockIdx.x * 256 + threadIdx.x;      // 0..1048575
    int dq  = idx & 127;
    int row = __builtin_amdgcn_readfirstlane(idx >> 7);   // wave-uniform
    const float* xr = xdbl + (size_t)row * 64;
    float4 z = ((const float4*)dtb)[dq];
    #pragma unroll
    for (int r = 0; r < DR; ++r) {
        float xv = xr[r];
        float4 w4 = *(const float4*)(WdtT + r * DM + dq * 4);
        z.x = fmaf(xv, w4.x, z.x); z.y = fmaf(xv, w4.y, z.y);
        z.z = fmaf(xv, w4.z, z.z); z.w = fmaf(xv, w4.w, z.w);
    }
    float4 sp;
    sp.x = fmaxf(z.x, 0.f) + log1pf(__expf(-fabsf(z.x)));
    sp.y = fmaxf(z.y, 0.f) + log1pf(__expf(-fabsf(z.y)));
    sp.z = fmaxf(z.z, 0.f) + log1pf(__expf(-fabsf(z.z)));
    sp.w = fmaxf(z.w, 0.f) + log1pf(__expf(-fabsf(z.w)));
    *(float4*)(dtw + (size_t)row * DM + dq * 4) = sp;
}

// ---------------- scan1: per-chunk local scan; lane = (dlocal, nq), 4 states ----------------
// wave covers 16 d x 4 n-quads. 8 blocks per (b,c); block = 4 waves = 64 d.
__global__ void __launch_bounds__(256) k_scan1(
        const float* __restrict__ dtw, const float* __restrict__ xc,
        const float* __restrict__ xdbl, const float* __restrict__ A2,
        float* __restrict__ S, float* __restrict__ dtsum) {
    int lane   = threadIdx.x & 63;
    int wv     = threadIdx.x >> 6;
    int dlocal = lane & 15;
    int nq     = lane >> 4;
    int db8    = blockIdx.x & 7;
    int c      = blockIdx.x >> 3;
    int b      = blockIdx.y;
    int d      = (db8 * 4 + wv) * 16 + dlocal;

    float4 a2 = *(const float4*)(A2 + (size_t)d * DS + nq * 4);
    float h0 = 0.f, h1 = 0.f, h2 = 0.f, h3 = 0.f;
    float dsum = 0.f;

    int l0 = c * CL;
    const float* dtp = dtw  + ((size_t)(b * L_SEQ + l0)) * DM + d;
    const float* xcp = xc   + ((size_t)(b * L_SEQ + l0)) * DM + d;
    const float* bp  = xdbl + ((size_t)(b * L_SEQ + l0)) * 64 + DR + nq * 4;

    #pragma unroll 4
    for (int i = 0; i < CL; ++i) {
        float dt = dtp[(size_t)i * DM];
        float xv = xcp[(size_t)i * DM];
        float4 B4 = *(const float4*)(bp + (size_t)i * 64);
        float u = dt * xv;
        dsum += dt;
        float dA;
        dA = exp2f(dt * a2.x); h0 = fmaf(dA, h0, u * B4.x);
        dA = exp2f(dt * a2.y); h1 = fmaf(dA, h1, u * B4.y);
        dA = exp2f(dt * a2.z); h2 = fmaf(dA, h2, u * B4.z);
        dA = exp2f(dt * a2.w); h3 = fmaf(dA, h3, u * B4.w);
    }

    float4 sv; sv.x = h0; sv.y = h1; sv.z = h2; sv.w = h3;
    *(float4*)(S + (size_t)c * NBDN + ((size_t)(b * DM + d)) * DS + nq * 4) = sv;
    if (nq == 0)
        dtsum[c * (NBATCH * DM) + b * DM + d] = dsum;
}

// ---------------- scan2: cross-chunk prefix; P from dtsum telescope; in-place Hin ----------------
__global__ void k_scan2(const float* __restrict__ dtsum, const float* __restrict__ A2,
                        float* __restrict__ S) {
    int t  = blockIdx.x * 256 + threadIdx.x;       // 0..32767
    float a2 = A2[t & (DM * DS - 1)];
    int bd = t >> 4;                               // b*DM+d
    float H = 0.f;
    #pragma unroll 8
    for (int c = 0; c < NCH; ++c) {
        float p = exp2f(a2 * dtsum[c * (NBATCH * DM) + bd]);
        float s = S[(size_t)c * NBDN + t];
        S[(size_t)c * NBDN + t] = H;               // Hin for chunk c
        H = fmaf(p, H, s);
    }
}

// ---------------- scan3: replay chunk from Hin, emit y ----------------
__global__ void __launch_bounds__(256) k_scan3(
        const float* __restrict__ dtw, const float* __restrict__ xc,
        const float* __restrict__ xdbl, const float* __restrict__ A2,
        const float* __restrict__ Dvec, const float* __restrict__ Hin,
        float* __restrict__ out) {
    int lane   = threadIdx.x & 63;
    int wv     = threadIdx.x >> 6;
    int dlocal = lane & 15;
    int nq     = lane >> 4;
    int db8    = blockIdx.x & 7;
    int c      = blockIdx.x >> 3;
    int b      = blockIdx.y;
    int d      = (db8 * 4 + wv) * 16 + dlocal;

    float4 a2 = *(const float4*)(A2 + (size_t)d * DS + nq * 4);
    float Dv = Dvec[d];
    float4 hv = *(const float4*)(Hin + (size_t)c * NBDN + ((size_t)(b * DM + d)) * DS + nq * 4);
    float h0 = hv.x, h1 = hv.y, h2 = hv.z, h3 = hv.w;

    int l0 = c * CL;
    const float* dtp = dtw  + ((size_t)(b * L_SEQ + l0)) * DM + d;
    const float* xcp = xc   + ((size_t)(b * L_SEQ + l0)) * DM + d;
    const float* bp  = xdbl + ((size_t)(b * L_SEQ + l0)) * 64 + DR + nq * 4;
    float* op = out + ((size_t)(b * L_SEQ + l0)) * DM + d;

    #pragma unroll 4
    for (int i = 0; i < CL; ++i) {
        float dt = dtp[(size_t)i * DM];
        float xv = xcp[(size_t)i * DM];
        float4 B4 = *(const float4*)(bp + (size_t)i * 64);
        float4 C4 = *(const float4*)(bp + (size_t)i * 64 + DS);
        float u = dt * xv;
        float dA;
        dA = exp2f(dt * a2.x); h0 = fmaf(dA, h0, u * B4.x);
        dA = exp2f(dt * a2.y); h1 = fmaf(dA, h1, u * B4.y);
        dA = exp2f(dt * a2.z); h2 = fmaf(dA, h2, u * B4.z);
        dA = exp2f(dt * a2.w); h3 = fmaf(dA, h3, u * B4.w);
        float p = fmaf(h3, C4.w, fmaf(h2, C4.z, fmaf(h1, C4.y, h0 * C4.x)));
        p += __shfl_xor(p, 16);
        p += __shfl_xor(p, 32);
        if (nq == 0) op[(size_t)i * DM] = fmaf(xv, Dv, p);
    }
}

extern "C" void kernel_launch(void* const* d_in, const int* in_sizes, int n_in,
                              void* d_out, int out_size, void* d_ws, size_t ws_size,
                              hipStream_t stream) {
    const float* x      = (const float*)d_in[0];
    const float* A_log  = (const float*)d_in[1];
    const float* Dvec   = (const float*)d_in[2];
    const float* Wx     = (const float*)d_in[3];
    const float* Wdt    = (const float*)d_in[4];
    const float* dtb    = (const float*)d_in[5];
    const float* convw  = (const float*)d_in[6];
    const float* convb  = (const float*)d_in[7];
    float* out = (float*)d_out;
    float* ws  = (float*)d_ws;

    float* xc    = ws + WS_XC;
    float* dtw   = ws + WS_DT;
    float* xdbl  = ws + WS_XDBL;
    float* WxT   = ws + WS_WXT;
    float* WdtT  = ws + WS_WDTT;
    float* A2    = ws + WS_A2;
    float* dtsum = ws + WS_DTSUM;
    float* S     = ws + WS_S;
    float* part  = ws + WS_PART;   // aliases S; dead before k_scan1 writes S

    k_prep<<<128, 256, 0, stream>>>(Wx, Wdt, A_log, WxT, WdtT, A2);
    k_conv<<<4096, 256, 0, stream>>>(x, convw, convb, xc);
    k_proj1a<<<1024, 256, 0, stream>>>(xc, WxT, part);
    k_proj1b<<<2048, 256, 0, stream>>>(part, xdbl);
    k_proj2<<<4096, 256, 0, stream>>>(xdbl, WdtT, dtb, dtw);
    k_scan1<<<dim3(8 * NCH, NBATCH), 256, 0, stream>>>(dtw, xc, xdbl, A2, S, dtsum);
    k_scan2<<<128, 256, 0, stream>>>(dtsum, A2, S);
    k_scan3<<<dim3(8 * NCH, NBATCH), 256, 0, stream>>>(dtw, xc, xdbl, A2, Dvec, S, out);
}

// Round 7
// 96.767 us; speedup vs baseline: 1.5073x; 1.2782x over previous
//
#include <hip/hip_runtime.h>

#define L_SEQ   2048
#define NBATCH  4
#define DM      512
#define DS      16
#define DR      32
#define NROWS   8192
#define NBDN    32768         // NBATCH*DM*DS chains
#define NCH     64            // chunks
#define CL      32            // chunk length
#define LOG2E   1.4426950408889634f

// ws layout (float offsets)
#define WS_XC    0            // 4194304  xc row-major [b,l][d]
#define WS_DT    4194304      // 4194304  dt row-major [b,l][d]
#define WS_XDBL  8388608      // 524288   x_dbl [row][64] (dt-raw | B | C)
#define WS_WXT   8912896      // 32768    WxT[d][j]
#define WS_WDTT  8945664      // 16384    WdtT[r][d]
#define WS_A2    8962048      // 8192     A2[d][n] = -exp(A_log)*log2e
#define WS_DTSUM 8970240      // 131072   dtsum[c][b*DM+d]
#define WS_S     9101312      // 2097152  S[c][chain]; scan2 rewrites in-place to Hin
// total 11198464 floats = 44.8 MB

// ---------------- weight transposes + A2 precompute ----------------
__global__ void k_prep(const float* __restrict__ Wx, const float* __restrict__ Wdt,
                       const float* __restrict__ A_log,
                       float* __restrict__ WxT, float* __restrict__ WdtT,
                       float* __restrict__ A2) {
    int idx = blockIdx.x * 256 + threadIdx.x;
    if (idx < DM * 64) {                 // WxT[d][j] = Wx[j][d]
        int d = idx >> 6, j = idx & 63;
        WxT[idx] = Wx[j * DM + d];
    }
    if (idx < DR * DM) {                 // WdtT[r][d] = Wdt[d][r]
        int r = idx >> 9, d = idx & 511;
        WdtT[idx] = Wdt[d * DR + r];
    }
    if (idx < DM * DS)                   // A2[d][n]
        A2[idx] = -__expf(A_log[idx]) * LOG2E;
}

// ---------------- fused front-end: conv + proj1 (K-split in-block) + proj2 ----------------
// 1024 blocks x 256 threads; block handles 8 consecutive rows (never straddles batch).
__global__ void __launch_bounds__(256) k_front(
        const float* __restrict__ x, const float* __restrict__ convw,
        const float* __restrict__ convb, const float* __restrict__ WxT,
        const float* __restrict__ WdtT, const float* __restrict__ dtb,
        float* __restrict__ xc, float* __restrict__ xdbl, float* __restrict__ dtw) {
    __shared__ float xcs[8][512];     // conv output tile
    __shared__ float pt[4][8][64];    // per-wave K-split partials
    __shared__ float xds[8][64];      // reduced x_dbl rows
    int t  = threadIdx.x;
    int r0 = blockIdx.x * 8;
    int b  = r0 >> 11, l0 = r0 & (L_SEQ - 1);
    int dq = t & 127, half = t >> 7;

    // ---- phase A: depthwise causal conv (K=4), float4 over d ----
    {
        const float4* wp = (const float4*)convw;
        float4 w0 = wp[dq * 4 + 0], w1 = wp[dq * 4 + 1];
        float4 w2 = wp[dq * 4 + 2], w3 = wp[dq * 4 + 3];
        float4 bias = ((const float4*)convb)[dq];
        #pragma unroll
        for (int i = 0; i < 4; ++i) {
            int row = half * 4 + i;
            int l   = l0 + row;
            const float* xr = x + ((size_t)(b * L_SEQ + l)) * DM + dq * 4;
            float4 acc = bias;
            float4 xv = *(const float4*)xr;
            acc.x = fmaf(xv.x, w0.w, acc.x); acc.y = fmaf(xv.y, w1.w, acc.y);
            acc.z = fmaf(xv.z, w2.w, acc.z); acc.w = fmaf(xv.w, w3.w, acc.w);
            if (l >= 1) {
                xv = *(const float4*)(xr - DM);
                acc.x = fmaf(xv.x, w0.z, acc.x); acc.y = fmaf(xv.y, w1.z, acc.y);
                acc.z = fmaf(xv.z, w2.z, acc.z); acc.w = fmaf(xv.w, w3.z, acc.w);
            }
            if (l >= 2) {
                xv = *(const float4*)(xr - 2 * DM);
                acc.x = fmaf(xv.x, w0.y, acc.x); acc.y = fmaf(xv.y, w1.y, acc.y);
                acc.z = fmaf(xv.z, w2.y, acc.z); acc.w = fmaf(xv.w, w3.y, acc.w);
            }
            if (l >= 3) {
                xv = *(const float4*)(xr - 3 * DM);
                acc.x = fmaf(xv.x, w0.x, acc.x); acc.y = fmaf(xv.y, w1.x, acc.y);
                acc.z = fmaf(xv.z, w2.x, acc.z); acc.w = fmaf(xv.w, w3.x, acc.w);
            }
            *(float4*)(&xcs[row][dq * 4]) = acc;
            *(float4*)(xc + ((size_t)(b * L_SEQ + l)) * DM + dq * 4) = acc;
        }
    }
    __syncthreads();

    // ---- phase B: proj1, wave wv owns K-slice [wv*128, wv*128+128) ----
    {
        int wv = t >> 6, j = t & 63;
        int k0 = wv * 128;
        float acc[8] = {0.f, 0.f, 0.f, 0.f, 0.f, 0.f, 0.f, 0.f};
        const float* wp = WxT + (size_t)k0 * 64 + j;
        for (int k4 = 0; k4 < 32; ++k4) {
            float4 xr[8];
            #pragma unroll
            for (int ri = 0; ri < 8; ++ri)
                xr[ri] = *(const float4*)(&xcs[ri][k0 + k4 * 4]);   // wave-uniform broadcast
            #pragma unroll
            for (int kk = 0; kk < 4; ++kk) {
                float w = wp[(k4 * 4 + kk) * 64];
                acc[0] = fmaf(((const float*)&xr[0])[kk], w, acc[0]);
                acc[1] = fmaf(((const float*)&xr[1])[kk], w, acc[1]);
                acc[2] = fmaf(((const float*)&xr[2])[kk], w, acc[2]);
                acc[3] = fmaf(((const float*)&xr[3])[kk], w, acc[3]);
                acc[4] = fmaf(((const float*)&xr[4])[kk], w, acc[4]);
                acc[5] = fmaf(((const float*)&xr[5])[kk], w, acc[5]);
                acc[6] = fmaf(((const float*)&xr[6])[kk], w, acc[6]);
                acc[7] = fmaf(((const float*)&xr[7])[kk], w, acc[7]);
            }
        }
        #pragma unroll
        for (int ri = 0; ri < 8; ++ri) pt[wv][ri][j] = acc[ri];
    }
    __syncthreads();

    // ---- reduce the 4 K-slices -> xds + global xdbl ----
    #pragma unroll
    for (int o = t; o < 512; o += 256) {
        int row = o >> 6, j2 = o & 63;
        float s = (pt[0][row][j2] + pt[1][row][j2])
                + (pt[2][row][j2] + pt[3][row][j2]);
        xds[row][j2] = s;
        xdbl[(size_t)(r0 + row) * 64 + j2] = s;
    }
    __syncthreads();

    // ---- phase C: proj2 + softplus ----
    {
        float4 bias = ((const float4*)dtb)[dq];
        float4 z0 = bias, z1 = bias, z2 = bias, z3 = bias;
        for (int r = 0; r < DR; ++r) {
            float4 w4 = *(const float4*)(WdtT + r * DM + dq * 4);
            float x0 = xds[half * 4 + 0][r];
            float x1 = xds[half * 4 + 1][r];
            float x2 = xds[half * 4 + 2][r];
            float x3 = xds[half * 4 + 3][r];
            z0.x = fmaf(x0, w4.x, z0.x); z0.y = fmaf(x0, w4.y, z0.y);
            z0.z = fmaf(x0, w4.z, z0.z); z0.w = fmaf(x0, w4.w, z0.w);
            z1.x = fmaf(x1, w4.x, z1.x); z1.y = fmaf(x1, w4.y, z1.y);
            z1.z = fmaf(x1, w4.z, z1.z); z1.w = fmaf(x1, w4.w, z1.w);
            z2.x = fmaf(x2, w4.x, z2.x); z2.y = fmaf(x2, w4.y, z2.y);
            z2.z = fmaf(x2, w4.z, z2.z); z2.w = fmaf(x2, w4.w, z2.w);
            z3.x = fmaf(x3, w4.x, z3.x); z3.y = fmaf(x3, w4.y, z3.y);
            z3.z = fmaf(x3, w4.z, z3.z); z3.w = fmaf(x3, w4.w, z3.w);
        }
        float4 zz[4] = {z0, z1, z2, z3};
        #pragma unroll
        for (int i = 0; i < 4; ++i) {
            float4 zi = zz[i];
            float4 sp;
            sp.x = fmaxf(zi.x, 0.f) + log1pf(__expf(-fabsf(zi.x)));
            sp.y = fmaxf(zi.y, 0.f) + log1pf(__expf(-fabsf(zi.y)));
            sp.z = fmaxf(zi.z, 0.f) + log1pf(__expf(-fabsf(zi.z)));
            sp.w = fmaxf(zi.w, 0.f) + log1pf(__expf(-fabsf(zi.w)));
            int l = l0 + half * 4 + i;
            *(float4*)(dtw + ((size_t)(b * L_SEQ + l)) * DM + dq * 4) = sp;
        }
    }
}

// ---------------- scan1: per-chunk local scan; lane = (dlocal, nq), 4 states ----------------
__global__ void __launch_bounds__(256) k_scan1(
        const float* __restrict__ dtw, const float* __restrict__ xc,
        const float* __restrict__ xdbl, const float* __restrict__ A2,
        float* __restrict__ S, float* __restrict__ dtsum) {
    int lane   = threadIdx.x & 63;
    int wv     = threadIdx.x >> 6;
    int dlocal = lane & 15;
    int nq     = lane >> 4;
    int db8    = blockIdx.x & 7;
    int c      = blockIdx.x >> 3;
    int b      = blockIdx.y;
    int d      = (db8 * 4 + wv) * 16 + dlocal;

    float4 a2 = *(const float4*)(A2 + (size_t)d * DS + nq * 4);
    float h0 = 0.f, h1 = 0.f, h2 = 0.f, h3 = 0.f;
    float dsum = 0.f;

    int l0 = c * CL;
    const float* dtp = dtw  + ((size_t)(b * L_SEQ + l0)) * DM + d;
    const float* xcp = xc   + ((size_t)(b * L_SEQ + l0)) * DM + d;
    const float* bp  = xdbl + ((size_t)(b * L_SEQ + l0)) * 64 + DR + nq * 4;

    #pragma unroll 4
    for (int i = 0; i < CL; ++i) {
        float dt = dtp[(size_t)i * DM];
        float xv = xcp[(size_t)i * DM];
        float4 B4 = *(const float4*)(bp + (size_t)i * 64);
        float u = dt * xv;
        dsum += dt;
        float dA;
        dA = exp2f(dt * a2.x); h0 = fmaf(dA, h0, u * B4.x);
        dA = exp2f(dt * a2.y); h1 = fmaf(dA, h1, u * B4.y);
        dA = exp2f(dt * a2.z); h2 = fmaf(dA, h2, u * B4.z);
        dA = exp2f(dt * a2.w); h3 = fmaf(dA, h3, u * B4.w);
    }

    float4 sv; sv.x = h0; sv.y = h1; sv.z = h2; sv.w = h3;
    *(float4*)(S + (size_t)c * NBDN + ((size_t)(b * DM + d)) * DS + nq * 4) = sv;
    if (nq == 0)
        dtsum[c * (NBATCH * DM) + b * DM + d] = dsum;
}

// ---------------- scan2: cross-chunk prefix; P from dtsum telescope; in-place Hin ----------------
__global__ void k_scan2(const float* __restrict__ dtsum, const float* __restrict__ A2,
                        float* __restrict__ S) {
    int t  = blockIdx.x * 256 + threadIdx.x;       // 0..32767
    float a2 = A2[t & (DM * DS - 1)];
    int bd = t >> 4;                               // b*DM+d
    float H = 0.f;
    #pragma unroll 8
    for (int c = 0; c < NCH; ++c) {
        float p = exp2f(a2 * dtsum[c * (NBATCH * DM) + bd]);
        float s = S[(size_t)c * NBDN + t];
        S[(size_t)c * NBDN + t] = H;               // Hin for chunk c
        H = fmaf(p, H, s);
    }
}

// ---------------- scan3: replay chunk from Hin, emit y ----------------
__global__ void __launch_bounds__(256) k_scan3(
        const float* __restrict__ dtw, const float* __restrict__ xc,
        const float* __restrict__ xdbl, const float* __restrict__ A2,
        const float* __restrict__ Dvec, const float* __restrict__ Hin,
        float* __restrict__ out) {
    int lane   = threadIdx.x & 63;
    int wv     = threadIdx.x >> 6;
    int dlocal = lane & 15;
    int nq     = lane >> 4;
    int db8    = blockIdx.x & 7;
    int c      = blockIdx.x >> 3;
    int b      = blockIdx.y;
    int d      = (db8 * 4 + wv) * 16 + dlocal;

    float4 a2 = *(const float4*)(A2 + (size_t)d * DS + nq * 4);
    float Dv = Dvec[d];
    float4 hv = *(const float4*)(Hin + (size_t)c * NBDN + ((size_t)(b * DM + d)) * DS + nq * 4);
    float h0 = hv.x, h1 = hv.y, h2 = hv.z, h3 = hv.w;

    int l0 = c * CL;
    const float* dtp = dtw  + ((size_t)(b * L_SEQ + l0)) * DM + d;
    const float* xcp = xc   + ((size_t)(b * L_SEQ + l0)) * DM + d;
    const float* bp  = xdbl + ((size_t)(b * L_SEQ + l0)) * 64 + DR + nq * 4;
    float* op = out + ((size_t)(b * L_SEQ + l0)) * DM + d;

    #pragma unroll 4
    for (int i = 0; i < CL; ++i) {
        float dt = dtp[(size_t)i * DM];
        float xv = xcp[(size_t)i * DM];
        float4 B4 = *(const float4*)(bp + (size_t)i * 64);
        float4 C4 = *(const float4*)(bp + (size_t)i * 64 + DS);
        float u = dt * xv;
        float dA;
        dA = exp2f(dt * a2.x); h0 = fmaf(dA, h0, u * B4.x);
        dA = exp2f(dt * a2.y); h1 = fmaf(dA, h1, u * B4.y);
        dA = exp2f(dt * a2.z); h2 = fmaf(dA, h2, u * B4.z);
        dA = exp2f(dt * a2.w); h3 = fmaf(dA, h3, u * B4.w);
        float p = fmaf(h3, C4.w, fmaf(h2, C4.z, fmaf(h1, C4.y, h0 * C4.x)));
        p += __shfl_xor(p, 16);
        p += __shfl_xor(p, 32);
        if (nq == 0) op[(size_t)i * DM] = fmaf(xv, Dv, p);
    }
}

extern "C" void kernel_launch(void* const* d_in, const int* in_sizes, int n_in,
                              void* d_out, int out_size, void* d_ws, size_t ws_size,
                              hipStream_t stream) {
    const float* x      = (const float*)d_in[0];
    const float* A_log  = (const float*)d_in[1];
    const float* Dvec   = (const float*)d_in[2];
    const float* Wx     = (const float*)d_in[3];
    const float* Wdt    = (const float*)d_in[4];
    const float* dtb    = (const float*)d_in[5];
    const float* convw  = (const float*)d_in[6];
    const float* convb  = (const float*)d_in[7];
    float* out = (float*)d_out;
    float* ws  = (float*)d_ws;

    float* xc    = ws + WS_XC;
    float* dtw   = ws + WS_DT;
    float* xdbl  = ws + WS_XDBL;
    float* WxT   = ws + WS_WXT;
    float* WdtT  = ws + WS_WDTT;
    float* A2    = ws + WS_A2;
    float* dtsum = ws + WS_DTSUM;
    float* S     = ws + WS_S;

    k_prep<<<128, 256, 0, stream>>>(Wx, Wdt, A_log, WxT, WdtT, A2);
    k_front<<<1024, 256, 0, stream>>>(x, convw, convb, WxT, WdtT, dtb, xc, xdbl, dtw);
    k_scan1<<<dim3(8 * NCH, NBATCH), 256, 0, stream>>>(dtw, xc, xdbl, A2, S, dtsum);
    k_scan2<<<128, 256, 0, stream>>>(dtsum, A2, S);
    k_scan3<<<dim3(8 * NCH, NBATCH), 256, 0, stream>>>(dtw, xc, xdbl, A2, Dvec, S, out);
}

// Round 8
// 94.571 us; speedup vs baseline: 1.5423x; 1.0232x over previous
//
#include <hip/hip_runtime.h>
#include <stdint.h>

#define L_SEQ   2048
#define NBATCH  4
#define DM      512
#define DS      16
#define DR      32
#define NROWS   8192
#define NBDN    32768         // NBATCH*DM*DS chains
#define NCH     64            // chunks
#define CL      32            // chunk length
#define LOG2E   1.4426950408889634f

// ws layout (float/uint offsets)
#define WS_DX    0            // 4194304  packed (bf16 dt | bf16 xc) [b,l][d]
#define WS_XDBL  4194304      // 524288   x_dbl [row][64] (dt-raw | B | C) f32
#define WS_WXT   4718592      // 32768    WxT[d][j]
#define WS_WDTT  4751360      // 16384    WdtT[r][d]
#define WS_A2    4767744      // 8192     A2[d][n] = -exp(A_log)*log2e
#define WS_DTSUM 4775936      // 131072   dtsum[c][b*DM+d]
#define WS_S     4907008      // 2097152  S[c][chain]; scan2 rewrites in-place to Hin
// total 7004160 floats = 28.0 MB

__device__ __forceinline__ uint32_t bf16_rne_hi(float v) {   // bf16 in high 16 bits
    uint32_t u = __float_as_uint(v);
    u += 0x7FFF + ((u >> 16) & 1);
    return u & 0xFFFF0000u;
}

// ---------------- weight transposes + A2 precompute ----------------
__global__ void k_prep(const float* __restrict__ Wx, const float* __restrict__ Wdt,
                       const float* __restrict__ A_log,
                       float* __restrict__ WxT, float* __restrict__ WdtT,
                       float* __restrict__ A2) {
    int idx = blockIdx.x * 256 + threadIdx.x;
    if (idx < DM * 64) {                 // WxT[d][j] = Wx[j][d]
        int d = idx >> 6, j = idx & 63;
        WxT[idx] = Wx[j * DM + d];
    }
    if (idx < DR * DM) {                 // WdtT[r][d] = Wdt[d][r]
        int r = idx >> 9, d = idx & 511;
        WdtT[idx] = Wdt[d * DR + r];
    }
    if (idx < DM * DS)                   // A2[d][n]
        A2[idx] = -__expf(A_log[idx]) * LOG2E;
}

// ---------------- fused front-end: conv + proj1 (K-split) + proj2 + pack ----------------
// 1024 blocks x 256 threads; block handles 8 consecutive rows.
__global__ void __launch_bounds__(256) k_front(
        const float* __restrict__ x, const float* __restrict__ convw,
        const float* __restrict__ convb, const float* __restrict__ WxT,
        const float* __restrict__ WdtT, const float* __restrict__ dtb,
        uint32_t* __restrict__ dx, float* __restrict__ xdbl) {
    __shared__ float xcs[8][512];     // conv output tile
    __shared__ float pt[4][8][64];    // per-wave K-split partials
    __shared__ float xds[8][64];      // reduced x_dbl rows
    int t  = threadIdx.x;
    int r0 = blockIdx.x * 8;
    int b  = r0 >> 11, l0 = r0 & (L_SEQ - 1);
    int dq = t & 127, half = t >> 7;

    // ---- phase A: depthwise causal conv (K=4), float4 over d ----
    {
        const float4* wp = (const float4*)convw;
        float4 w0 = wp[dq * 4 + 0], w1 = wp[dq * 4 + 1];
        float4 w2 = wp[dq * 4 + 2], w3 = wp[dq * 4 + 3];
        float4 bias = ((const float4*)convb)[dq];
        #pragma unroll
        for (int i = 0; i < 4; ++i) {
            int row = half * 4 + i;
            int l   = l0 + row;
            const float* xr = x + ((size_t)(b * L_SEQ + l)) * DM + dq * 4;
            float4 acc = bias;
            float4 xv = *(const float4*)xr;
            acc.x = fmaf(xv.x, w0.w, acc.x); acc.y = fmaf(xv.y, w1.w, acc.y);
            acc.z = fmaf(xv.z, w2.w, acc.z); acc.w = fmaf(xv.w, w3.w, acc.w);
            if (l >= 1) {
                xv = *(const float4*)(xr - DM);
                acc.x = fmaf(xv.x, w0.z, acc.x); acc.y = fmaf(xv.y, w1.z, acc.y);
                acc.z = fmaf(xv.z, w2.z, acc.z); acc.w = fmaf(xv.w, w3.z, acc.w);
            }
            if (l >= 2) {
                xv = *(const float4*)(xr - 2 * DM);
                acc.x = fmaf(xv.x, w0.y, acc.x); acc.y = fmaf(xv.y, w1.y, acc.y);
                acc.z = fmaf(xv.z, w2.y, acc.z); acc.w = fmaf(xv.w, w3.y, acc.w);
            }
            if (l >= 3) {
                xv = *(const float4*)(xr - 3 * DM);
                acc.x = fmaf(xv.x, w0.x, acc.x); acc.y = fmaf(xv.y, w1.x, acc.y);
                acc.z = fmaf(xv.z, w2.x, acc.z); acc.w = fmaf(xv.w, w3.x, acc.w);
            }
            *(float4*)(&xcs[row][dq * 4]) = acc;
        }
    }
    __syncthreads();

    // ---- phase B: proj1, wave wv owns K-slice [wv*128, wv*128+128) ----
    {
        int wv = t >> 6, j = t & 63;
        int k0 = wv * 128;
        float acc[8] = {0.f, 0.f, 0.f, 0.f, 0.f, 0.f, 0.f, 0.f};
        const float* wp = WxT + (size_t)k0 * 64 + j;
        for (int k4 = 0; k4 < 32; ++k4) {
            float4 xr[8];
            #pragma unroll
            for (int ri = 0; ri < 8; ++ri)
                xr[ri] = *(const float4*)(&xcs[ri][k0 + k4 * 4]);   // wave-uniform broadcast
            #pragma unroll
            for (int kk = 0; kk < 4; ++kk) {
                float w = wp[(k4 * 4 + kk) * 64];
                acc[0] = fmaf(((const float*)&xr[0])[kk], w, acc[0]);
                acc[1] = fmaf(((const float*)&xr[1])[kk], w, acc[1]);
                acc[2] = fmaf(((const float*)&xr[2])[kk], w, acc[2]);
                acc[3] = fmaf(((const float*)&xr[3])[kk], w, acc[3]);
                acc[4] = fmaf(((const float*)&xr[4])[kk], w, acc[4]);
                acc[5] = fmaf(((const float*)&xr[5])[kk], w, acc[5]);
                acc[6] = fmaf(((const float*)&xr[6])[kk], w, acc[6]);
                acc[7] = fmaf(((const float*)&xr[7])[kk], w, acc[7]);
            }
        }
        #pragma unroll
        for (int ri = 0; ri < 8; ++ri) pt[wv][ri][j] = acc[ri];
    }
    __syncthreads();

    // ---- reduce the 4 K-slices -> xds + global xdbl ----
    #pragma unroll
    for (int o = t; o < 512; o += 256) {
        int row = o >> 6, j2 = o & 63;
        float s = (pt[0][row][j2] + pt[1][row][j2])
                + (pt[2][row][j2] + pt[3][row][j2]);
        xds[row][j2] = s;
        xdbl[(size_t)(r0 + row) * 64 + j2] = s;
    }
    __syncthreads();

    // ---- phase C: proj2 + softplus + pack (dt|xc) bf16 ----
    {
        float4 bias = ((const float4*)dtb)[dq];
        float4 z0 = bias, z1 = bias, z2 = bias, z3 = bias;
        for (int r = 0; r < DR; ++r) {
            float4 w4 = *(const float4*)(WdtT + r * DM + dq * 4);
            float x0 = xds[half * 4 + 0][r];
            float x1 = xds[half * 4 + 1][r];
            float x2 = xds[half * 4 + 2][r];
            float x3 = xds[half * 4 + 3][r];
            z0.x = fmaf(x0, w4.x, z0.x); z0.y = fmaf(x0, w4.y, z0.y);
            z0.z = fmaf(x0, w4.z, z0.z); z0.w = fmaf(x0, w4.w, z0.w);
            z1.x = fmaf(x1, w4.x, z1.x); z1.y = fmaf(x1, w4.y, z1.y);
            z1.z = fmaf(x1, w4.z, z1.z); z1.w = fmaf(x1, w4.w, z1.w);
            z2.x = fmaf(x2, w4.x, z2.x); z2.y = fmaf(x2, w4.y, z2.y);
            z2.z = fmaf(x2, w4.z, z2.z); z2.w = fmaf(x2, w4.w, z2.w);
            z3.x = fmaf(x3, w4.x, z3.x); z3.y = fmaf(x3, w4.y, z3.y);
            z3.z = fmaf(x3, w4.z, z3.z); z3.w = fmaf(x3, w4.w, z3.w);
        }
        float4 zz[4] = {z0, z1, z2, z3};
        #pragma unroll
        for (int i = 0; i < 4; ++i) {
            int row = half * 4 + i;
            float4 zi = zz[i];
            float4 sp;
            sp.x = fmaxf(zi.x, 0.f) + log1pf(__expf(-fabsf(zi.x)));
            sp.y = fmaxf(zi.y, 0.f) + log1pf(__expf(-fabsf(zi.y)));
            sp.z = fmaxf(zi.z, 0.f) + log1pf(__expf(-fabsf(zi.z)));
            sp.w = fmaxf(zi.w, 0.f) + log1pf(__expf(-fabsf(zi.w)));
            uint4 pk;
            pk.x = bf16_rne_hi(sp.x) | (bf16_rne_hi(xcs[row][dq * 4 + 0]) >> 16);
            pk.y = bf16_rne_hi(sp.y) | (bf16_rne_hi(xcs[row][dq * 4 + 1]) >> 16);
            pk.z = bf16_rne_hi(sp.z) | (bf16_rne_hi(xcs[row][dq * 4 + 2]) >> 16);
            pk.w = bf16_rne_hi(sp.w) | (bf16_rne_hi(xcs[row][dq * 4 + 3]) >> 16);
            *(uint4*)(dx + ((size_t)(b * L_SEQ + l0 + row)) * DM + dq * 4) = pk;
        }
    }
}

// ---------------- scan1: per-chunk local scan; lane = (dlocal, nq), 4 states ----------------
__global__ void __launch_bounds__(256) k_scan1(
        const uint32_t* __restrict__ dx, const float* __restrict__ xdbl,
        const float* __restrict__ A2, float* __restrict__ S,
        float* __restrict__ dtsum) {
    int lane   = threadIdx.x & 63;
    int wv     = threadIdx.x >> 6;
    int dlocal = lane & 15;
    int nq     = lane >> 4;
    int db8    = blockIdx.x & 7;
    int c      = blockIdx.x >> 3;
    int b      = blockIdx.y;
    int d      = (db8 * 4 + wv) * 16 + dlocal;

    float4 a2 = *(const float4*)(A2 + (size_t)d * DS + nq * 4);
    float h0 = 0.f, h1 = 0.f, h2 = 0.f, h3 = 0.f;
    float dsum = 0.f;

    int l0 = c * CL;
    const uint32_t* dxp = dx + ((size_t)(b * L_SEQ + l0)) * DM + d;
    const float*    bp  = xdbl + ((size_t)(b * L_SEQ + l0)) * 64 + DR + nq * 4;

    #pragma unroll 4
    for (int i = 0; i < CL; ++i) {
        uint32_t v = dxp[(size_t)i * DM];
        float dt = __uint_as_float(v & 0xFFFF0000u);
        float xv = __uint_as_float(v << 16);
        float4 B4 = *(const float4*)(bp + (size_t)i * 64);
        float u = dt * xv;
        dsum += dt;
        float dA;
        dA = exp2f(dt * a2.x); h0 = fmaf(dA, h0, u * B4.x);
        dA = exp2f(dt * a2.y); h1 = fmaf(dA, h1, u * B4.y);
        dA = exp2f(dt * a2.z); h2 = fmaf(dA, h2, u * B4.z);
        dA = exp2f(dt * a2.w); h3 = fmaf(dA, h3, u * B4.w);
    }

    float4 sv; sv.x = h0; sv.y = h1; sv.z = h2; sv.w = h3;
    *(float4*)(S + (size_t)c * NBDN + ((size_t)(b * DM + d)) * DS + nq * 4) = sv;
    if (nq == 0)
        dtsum[c * (NBATCH * DM) + b * DM + d] = dsum;
}

// ---------------- scan2: cross-chunk prefix; P from dtsum telescope; in-place Hin ----------------
__global__ void k_scan2(const float* __restrict__ dtsum, const float* __restrict__ A2,
                        float* __restrict__ S) {
    int t  = blockIdx.x * 256 + threadIdx.x;       // 0..32767
    float a2 = A2[t & (DM * DS - 1)];
    int bd = t >> 4;                               // b*DM+d
    float H = 0.f;
    #pragma unroll 8
    for (int c = 0; c < NCH; ++c) {
        float p = exp2f(a2 * dtsum[c * (NBATCH * DM) + bd]);
        float s = S[(size_t)c * NBDN + t];
        S[(size_t)c * NBDN + t] = H;               // Hin for chunk c
        H = fmaf(p, H, s);
    }
}

// ---------------- scan3: replay chunk from Hin, emit y ----------------
__global__ void __launch_bounds__(256) k_scan3(
        const uint32_t* __restrict__ dx, const float* __restrict__ xdbl,
        const float* __restrict__ A2, const float* __restrict__ Dvec,
        const float* __restrict__ Hin, float* __restrict__ out) {
    int lane   = threadIdx.x & 63;
    int wv     = threadIdx.x >> 6;
    int dlocal = lane & 15;
    int nq     = lane >> 4;
    int db8    = blockIdx.x & 7;
    int c      = blockIdx.x >> 3;
    int b      = blockIdx.y;
    int d      = (db8 * 4 + wv) * 16 + dlocal;

    float4 a2 = *(const float4*)(A2 + (size_t)d * DS + nq * 4);
    float Dv = Dvec[d];
    float4 hv = *(const float4*)(Hin + (size_t)c * NBDN + ((size_t)(b * DM + d)) * DS + nq * 4);
    float h0 = hv.x, h1 = hv.y, h2 = hv.z, h3 = hv.w;

    int l0 = c * CL;
    const uint32_t* dxp = dx + ((size_t)(b * L_SEQ + l0)) * DM + d;
    const float*    bp  = xdbl + ((size_t)(b * L_SEQ + l0)) * 64 + DR + nq * 4;
    float* op = out + ((size_t)(b * L_SEQ + l0)) * DM + d;

    #pragma unroll 4
    for (int i = 0; i < CL; ++i) {
        uint32_t v = dxp[(size_t)i * DM];
        float dt = __uint_as_float(v & 0xFFFF0000u);
        float xv = __uint_as_float(v << 16);
        float4 B4 = *(const float4*)(bp + (size_t)i * 64);
        float4 C4 = *(const float4*)(bp + (size_t)i * 64 + DS);
        float u = dt * xv;
        float dA;
        dA = exp2f(dt * a2.x); h0 = fmaf(dA, h0, u * B4.x);
        dA = exp2f(dt * a2.y); h1 = fmaf(dA, h1, u * B4.y);
        dA = exp2f(dt * a2.z); h2 = fmaf(dA, h2, u * B4.z);
        dA = exp2f(dt * a2.w); h3 = fmaf(dA, h3, u * B4.w);
        float p = fmaf(h3, C4.w, fmaf(h2, C4.z, fmaf(h1, C4.y, h0 * C4.x)));
        p += __shfl_xor(p, 16);
        p += __shfl_xor(p, 32);
        if (nq == 0) op[(size_t)i * DM] = fmaf(xv, Dv, p);
    }
}

extern "C" void kernel_launch(void* const* d_in, const int* in_sizes, int n_in,
                              void* d_out, int out_size, void* d_ws, size_t ws_size,
                              hipStream_t stream) {
    const float* x      = (const float*)d_in[0];
    const float* A_log  = (const float*)d_in[1];
    const float* Dvec   = (const float*)d_in[2];
    const float* Wx     = (const float*)d_in[3];
    const float* Wdt    = (const float*)d_in[4];
    const float* dtb    = (const float*)d_in[5];
    const float* convw  = (const float*)d_in[6];
    const float* convb  = (const float*)d_in[7];
    float* out = (float*)d_out;
    float* ws  = (float*)d_ws;

    uint32_t* dxp = (uint32_t*)(ws + WS_DX);
    float* xdbl  = ws + WS_XDBL;
    float* WxT   = ws + WS_WXT;
    float* WdtT  = ws + WS_WDTT;
    float* A2    = ws + WS_A2;
    float* dtsum = ws + WS_DTSUM;
    float* S     = ws + WS_S;

    k_prep<<<128, 256, 0, stream>>>(Wx, Wdt, A_log, WxT, WdtT, A2);
    k_front<<<1024, 256, 0, stream>>>(x, convw, convb, WxT, WdtT, dtb, dxp, xdbl);
    k_scan1<<<dim3(8 * NCH, NBATCH), 256, 0, stream>>>(dxp, xdbl, A2, S, dtsum);
    k_scan2<<<128, 256, 0, stream>>>(dtsum, A2, S);
    k_scan3<<<dim3(8 * NCH, NBATCH), 256, 0, stream>>>(dxp, xdbl, A2, Dvec, S, out);
}